// Round 5
// baseline (437.642 us; speedup 1.0000x reference)
//
#include <hip/hip_runtime.h>

// Embedding gather: out[r, :] = table[idx[r], :]
// rows = 819200, D = 64 fp32 (256 B/row), table 1M x 64 = 256 MB.
//
// v6: BUCKETED gather (DRAM page-locality theory).
//  Evidence so far: MLP unroll neutral (R3), NT stores neutral (R3),
//  L3 pre-warm useless (R4: +35us cost, zero gather benefit). The gather
//  (<155us/dispatch, est. ~85-100us) is bound by random 256B reads over
//  a 256MB footprint: ~1 access per DRAM page per controller window ->
//  all page-misses.
//  Fix: counting-scatter rows into 16 buckets by table partition
//  (idx>>16, 16MB windows), then gather bucket-by-bucket. Same-page
//  accesses now cluster in time (~6 accesses/2KB page per window slice)
//  -> row-buffer hits; any L2/L3 retouch capture concentrates too.
//  Rows stay ~ordered within buckets (block-ordered reservation), so
//  out-writes remain mostly ascending. Falls back to the plain v1-style
//  gather if the workspace is too small.

typedef float floatx4 __attribute__((ext_vector_type(4)));

#define LANES_PER_ROW 16
#define NBUCKET 16
#define BUCKET_SHIFT 16   // bucket = idx >> 16  (VOCAB = 1e6 < 2^20)
#define BUCKET_CAP 65536  // slots/bucket; expected max load ~53.7K (+54 sigma margin)

// --- Kernel A: bucketize rows by table partition of their index. ---
__global__ __launch_bounds__(256) void bucketize(
    const int* __restrict__ idx, int n_rows,
    int* __restrict__ gcnt, int2* __restrict__ pairs)
{
    __shared__ int cnt[NBUCKET];
    __shared__ int base[NBUCKET];
    int tid = threadIdx.x;
    if (tid < NBUCKET) cnt[tid] = 0;
    __syncthreads();

    int row = blockIdx.x * 256 + tid;
    bool valid = (row < n_rows);
    int t = 0, b = 0, pos = 0;
    if (valid) {
        t = idx[row];
        b = t >> BUCKET_SHIFT;
        pos = atomicAdd(&cnt[b], 1);       // LDS atomic: local position
    }
    __syncthreads();
    if (tid < NBUCKET)                     // one global reservation per bucket
        base[tid] = atomicAdd(&gcnt[tid], cnt[tid]);
    __syncthreads();
    if (valid) {
        int p = base[b] + pos;
        if (p < BUCKET_CAP)                // cannot overflow for uniform idx
            pairs[b * BUCKET_CAP + p] = make_int2(row, t);
    }
}

// --- Kernel B: gather in bucket order (reads concentrated per 16MB window). ---
__global__ __launch_bounds__(256) void gather_bucketed(
    const int* __restrict__ gcnt, const int2* __restrict__ pairs,
    const floatx4* __restrict__ table, floatx4* __restrict__ out)
{
    int gid   = blockIdx.x * 256 + threadIdx.x;
    int entry = gid >> 4;                  // one 16-lane group per entry
    int lane  = gid & 15;
    int b     = entry >> 16;               // BUCKET_CAP == 2^16
    int slot  = entry & (BUCKET_CAP - 1);
    if (slot >= gcnt[b]) return;           // empty tail of this bucket
    int2 pr = pairs[entry];                // (row, t), broadcast in group
    floatx4 v = table[(long long)pr.y * LANES_PER_ROW + lane];
    __builtin_nontemporal_store(v, out + (long long)pr.x * LANES_PER_ROW + lane);
}

// --- Fallback: plain gather (v1 structure, best measured 391.5us). ---
__global__ __launch_bounds__(256) void hh_embed_gather(
    const int* __restrict__ idx,
    const floatx4* __restrict__ table,
    floatx4* __restrict__ out,
    int n_rows)
{
    int tid  = blockIdx.x * blockDim.x + threadIdx.x;
    int row  = tid >> 4;
    int lane = tid & 15;
    if (row >= n_rows) return;
    int t = idx[row];
    floatx4 v = table[(long long)t * LANES_PER_ROW + lane];
    __builtin_nontemporal_store(v, out + (long long)row * LANES_PER_ROW + lane);
}

extern "C" void kernel_launch(void* const* d_in, const int* in_sizes, int n_in,
                              void* d_out, int out_size, void* d_ws, size_t ws_size,
                              hipStream_t stream) {
    const int*   idx   = (const int*)d_in[0];     // [B*F] int32
    const float* table = (const float*)d_in[1];   // [V, 64] fp32
    float*       out   = (float*)d_out;           // [B*F, 64] fp32
    int n_rows = in_sizes[0];                     // 819200

    size_t need = 256 + (size_t)NBUCKET * BUCKET_CAP * sizeof(int2); // 256B + 8MB
    bool can_bucket = (ws_size >= need) && (n_rows <= NBUCKET * BUCKET_CAP);

    if (can_bucket) {
        int*  gcnt  = (int*)d_ws;                       // 16 counters
        int2* pairs = (int2*)((char*)d_ws + 256);       // 16 x 65536 entries

        hipMemsetAsync(d_ws, 0, 256, stream);           // zero counters

        int gridA = (n_rows + 255) / 256;               // 3200
        bucketize<<<gridA, 256, 0, stream>>>(idx, n_rows, gcnt, pairs);

        long long slots = (long long)NBUCKET * BUCKET_CAP;      // 1,048,576
        int gridB = (int)(slots * LANES_PER_ROW / 256);         // 65,536
        gather_bucketed<<<gridB, 256, 0, stream>>>(
            gcnt, pairs, (const floatx4*)table, (floatx4*)out);
    } else {
        long long total_threads = (long long)n_rows * LANES_PER_ROW;
        int grid = (int)((total_threads + 255) / 256);
        hh_embed_gather<<<grid, 256, 0, stream>>>(
            idx, (const floatx4*)table, (floatx4*)out, n_rows);
    }
}